// Round 1
// 344.065 us; speedup vs baseline: 1.0402x; 1.0402x over previous
//
#include <hip/hip_runtime.h>

// GatedRecurrentCell: pa/pi = x@W^T + b (fp16 MFMA) with gates FUSED into the
// GEMM epilogue; (a,c) stored fp16; chunked linear scan (64 chunks x 32 steps).
// Shapes: B=8 S=2048 D=512 I=2048. M=B*S=16384, N2=2*I=4096, K=D=512.
// W layout: interleaved rows (2i=Wa_i, 2i+1=Wi_i) so each n-tile holds (pa,pi)
// pairs for 64 i's -> epilogue computes a,c + 32-step chunk aggregates in-block.
// R1: gemm_gate restructured: LDS double-buffer with prefetch-before-compute
// (1 barrier/K-step instead of 2, stage latency hidden under MFMA) + XOR slot
// swizzle (slot ^= (row>>1)&3) applied as pre-swizzled global source + swizzled
// ds_read (LDS dest stays linear for global_load_lds). scan_out widened to
// 4 i's/thread (f16x8 loads / float4 stores).
// ws: [0,16Mi) x_f16 | [16,20Mi) W_f16 | [20Mi,+128Mi) AC f16 | +8Mi agg | +4Mi carry

#define LOG2_3 1.5849625007211562f

typedef _Float16 f16x8 __attribute__((ext_vector_type(8)));
typedef _Float16 f16x4 __attribute__((ext_vector_type(4)));
typedef _Float16 f16x2 __attribute__((ext_vector_type(2)));
typedef float f32x4 __attribute__((ext_vector_type(4)));

__device__ __forceinline__ float sigmoidf_(float v) {
  return 1.0f / (1.0f + __expf(-v));
}

__device__ __forceinline__ void async_copy16(void* lds, const void* gp) {
  __builtin_amdgcn_global_load_lds((__attribute__((address_space(1))) void*)gp,
                                   (__attribute__((address_space(3))) void*)lds,
                                   16, 0, 0);
}

// x -> xh (plain). Wa/Wi -> wh with row interleave: wh row 2i = Wa_i, 2i+1 = Wi_i.
__global__ __launch_bounds__(256) void cvt_all(const float* __restrict__ x,
                                               const float* __restrict__ Wa,
                                               const float* __restrict__ Wi,
                                               _Float16* __restrict__ xh,
                                               _Float16* __restrict__ wh) {
  int idx = blockIdx.x * 256 + threadIdx.x;
  const float* src;
  _Float16* dst;
  int off, doff;
  if (idx < 2097152) {
    src = x; dst = xh; off = idx; doff = idx;
  } else if (idx < 2097152 + 262144) {
    src = Wa; dst = wh; off = idx - 2097152;
    doff = off + ((off >> 7) << 7);          // (2i)*128 + k4
  } else {
    src = Wi; dst = wh; off = idx - 2359296;
    doff = off + ((off >> 7) << 7) + 128;    // (2i+1)*128 + k4
  }
  float4 v = ((const float4*)src)[off];
  f16x4 h;
  h[0] = (_Float16)v.x;
  h[1] = (_Float16)v.y;
  h[2] = (_Float16)v.z;
  h[3] = (_Float16)v.w;
  ((f16x4*)dst)[doff] = h;
}

__device__ __forceinline__ void gate_ac(float pa, float pi, float alpha, float& a, float& c) {
  float rg = sigmoidf_(pa);
  a = alpha * exp2f(-LOG2_3 * rg);
  float ig = sigmoidf_(pi);
  c = sqrtf(fmaxf(1.0f - a * a, 0.0f)) * (ig * pi);
}

// GEMM 128x128 tile + fused gate epilogue.
// AC[m][2i..2i+1] = (a,c) fp16. agg[(b*64+ch)][i] = (A,H) over 32-step chunk.
// LDS layout per K-buffer (4096 f16 A + 4096 f16 B), double-buffered:
//   buf0 = smem[0,8192), buf1 = smem[8192,16384). Epilogue reuses smem[0,8704).
// Swizzle: 16B slot s at row r holds logical slot s ^ ((r>>1)&3). Staging keeps
// the LDS dest linear (t*16B, required by global_load_lds) and pre-swizzles the
// GLOBAL source column; reads apply the same XOR (involution).
__global__ __launch_bounds__(256) void gemm_gate(const _Float16* __restrict__ Ah,
                                                 const _Float16* __restrict__ Wh,
                                                 const float* __restrict__ ba,
                                                 const float* __restrict__ bi,
                                                 const float* __restrict__ gate,
                                                 _Float16* __restrict__ AC,
                                                 float2* __restrict__ agg) {
  constexpr int K = 512;
  constexpr int N2 = 4096;
  __shared__ __align__(16) _Float16 smem[16384];  // 32 KiB: 2 x (As 4096 | Bs 4096)
  __shared__ float pAs[8 * 65];                   // partials, padded stride 65
  __shared__ float pHs[8 * 65];
  const int t = threadIdx.x;
  const int mBase = blockIdx.y * 128;
  const int nBase = blockIdx.x * 128;
  const int r = t >> 2;                      // staged row (0..63; +64 for 2nd half)
  const int p = t & 3;                       // physical 16B slot within row
  const int lsw = p ^ ((r >> 1) & 3);        // logical slot to fetch for this dest
  const _Float16* gA0 = Ah + (size_t)(mBase + r) * K + lsw * 8;
  const _Float16* gB0 = Wh + (size_t)(nBase + r) * K + lsw * 8;
  const int ldst = r * 32 + p * 8;           // f16 idx; byte off == t*16 (linear)

  const int lane = t & 63;
  const int wave = t >> 6;
  const int wm = (wave & 1) * 64;
  const int wn = (wave >> 1) * 64;
  const int lrow = lane & 15;
  const int quad = lane >> 4;
  // read-side swizzled slot: row = (16-mult) + lrow -> f(row) = (lrow>>1)&3
  const int xq = quad ^ ((lrow >> 1) & 3);

  f32x4 acc[4][4];
#pragma unroll
  for (int i = 0; i < 4; ++i)
#pragma unroll
    for (int j = 0; j < 4; ++j)
      acc[i][j] = (f32x4)0.0f;

  _Float16* b0 = smem;
  _Float16* b1 = smem + 8192;

  // prologue: stage K-tile 0 into buf0
  async_copy16(b0 + ldst, gA0);
  async_copy16(b0 + 2048 + ldst, gA0 + (size_t)64 * K);
  async_copy16(b0 + 4096 + ldst, gB0);
  async_copy16(b0 + 6144 + ldst, gB0 + (size_t)64 * K);
  __syncthreads();

#pragma unroll
  for (int kt = 0; kt < 16; ++kt) {
    _Float16* cur = (kt & 1) ? b1 : b0;
    _Float16* nxt = (kt & 1) ? b0 : b1;
    if (kt < 15) {
      const int ko = (kt + 1) * 32;
      async_copy16(nxt + ldst, gA0 + ko);
      async_copy16(nxt + 2048 + ldst, gA0 + (size_t)64 * K + ko);
      async_copy16(nxt + 4096 + ldst, gB0 + ko);
      async_copy16(nxt + 6144 + ldst, gB0 + (size_t)64 * K + ko);
    }
    f16x8 af[4], bf[4];
#pragma unroll
    for (int i = 0; i < 4; ++i)
      af[i] = *(const f16x8*)(cur + (wm + i * 16 + lrow) * 32 + xq * 8);
#pragma unroll
    for (int j = 0; j < 4; ++j)
      bf[j] = *(const f16x8*)(cur + 4096 + (wn + j * 16 + lrow) * 32 + xq * 8);
#pragma unroll
    for (int i = 0; i < 4; ++i)
#pragma unroll
      for (int j = 0; j < 4; ++j)
        acc[i][j] = __builtin_amdgcn_mfma_f32_16x16x32_f16(af[i], bf[j], acc[i][j], 0, 0, 0);
    // one barrier per K-step: drains prefetch (vmcnt) + all frag reads (lgkm),
    // so next iter may read nxt and overwrite cur.
    __syncthreads();
  }

  // bias: col n even -> ba[n/2] (pa), odd -> bi[n/2] (pi)
  float bias[4];
#pragma unroll
  for (int j = 0; j < 4; ++j) {
    const int n = nBase + wn + j * 16 + lrow;
    bias[j] = (n & 1) ? bi[n >> 1] : ba[n >> 1];
  }

  // gate-phase thread roles: col = i-lane 0..63, q = s-quarter (16 rows each)
  const int col = t & 63;
  const int q = t >> 6;
  const float alpha = sigmoidf_(gate[(nBase >> 1) + col]);
  const int b = blockIdx.y >> 4;  // 16 m-tiles per batch

  // 2 rounds of 64 m-rows: stage C+bias -> LDS, compute a,c, store AC, local scan.
  // C/D layout: col = lane&15, row = quad*4 + reg (m89-verified)
#pragma unroll
  for (int h = 0; h < 2; ++h) {
    if (wm == h * 64) {
#pragma unroll
      for (int i = 0; i < 4; ++i)
#pragma unroll
        for (int j = 0; j < 4; ++j)
#pragma unroll
          for (int rr = 0; rr < 4; ++rr)
            smem[(i * 16 + quad * 4 + rr) * 136 + wn + j * 16 + lrow] =
                (_Float16)(acc[i][j][rr] + bias[j]);
    }
    __syncthreads();
    float A = 1.0f, Hn = 0.0f;
    _Float16* ACp = AC + (size_t)(mBase + h * 64 + q * 16) * N2 + nBase + 2 * col;
#pragma unroll 4
    for (int rs = 0; rs < 16; ++rs) {
      f16x2 pp = *(const f16x2*)(smem + (q * 16 + rs) * 136 + 2 * col);
      float a, c;
      gate_ac((float)pp[0], (float)pp[1], alpha, a, c);
      f16x2 o;
      o[0] = (_Float16)a;
      o[1] = (_Float16)c;
      *(f16x2*)ACp = o;
      ACp += N2;
      A *= a;
      Hn = fmaf(a, Hn, c);
    }
    pAs[(h * 4 + q) * 65 + col] = A;
    pHs[(h * 4 + q) * 65 + col] = Hn;
    __syncthreads();
  }

  // combine 8x16-step partials -> 4x32-step aggregates (s-ascending pairs)
  if (t < 64) {
#pragma unroll
    for (int k = 0; k < 4; ++k) {
      float A0 = pAs[(2 * k) * 65 + t], H0 = pHs[(2 * k) * 65 + t];
      float A1 = pAs[(2 * k + 1) * 65 + t], H1 = pHs[(2 * k + 1) * 65 + t];
      const int ch = ((blockIdx.y & 15) << 2) + k;
      agg[((size_t)(b * 64 + ch)) * 2048 + (nBase >> 1) + t] =
          make_float2(A0 * A1, fmaf(A1, H0, H1));
    }
  }
}

__global__ __launch_bounds__(64) void scan_pass2(const float2* __restrict__ agg,
                                                 float* __restrict__ carry) {
  const int i = blockIdx.x * 64 + threadIdx.x;  // grid.x=32 -> 0..2047
  const int b = blockIdx.y;
  float h = 0.0f;
  for (int c8 = 0; c8 < 8; ++c8) {
    float2 aH[8];
#pragma unroll
    for (int u = 0; u < 8; ++u)
      aH[u] = agg[((size_t)(b * 64 + c8 * 8 + u)) * 2048 + i];
#pragma unroll
    for (int u = 0; u < 8; ++u) {
      carry[((size_t)(b * 64 + c8 * 8 + u)) * 2048 + i] = h;
      h = fmaf(aH[u].x, h, aH[u].y);
    }
  }
}

// Pure fma replay: h = a*h + c, no transcendentals. 4 i's per thread,
// f16x8 (16B) loads + float4 (16B) stores.
__global__ __launch_bounds__(256) void scan_out(const _Float16* __restrict__ AC,
                                                const float* __restrict__ carry,
                                                float* __restrict__ out) {
  const int tt = blockIdx.x * 256 + threadIdx.x;  // 0..511 (4 i's per thread)
  const int i0 = tt * 4;
  const int ch = blockIdx.y;  // 0..63
  const int b = blockIdx.z;
  const float4 cr = ((const float4*)(carry + ((size_t)(b * 64 + ch)) * 2048))[tt];
  float h0 = cr.x, h1 = cr.y, h2 = cr.z, h3 = cr.w;
  const _Float16* row = AC + ((size_t)(b * 2048 + ch * 32)) * 4096 + i0 * 2;
  float* orow = out + ((size_t)(b * 2048 + ch * 32)) * 2048 + i0;
  for (int s4 = 0; s4 < 8; ++s4) {
    f16x8 v[4];
#pragma unroll
    for (int u = 0; u < 4; ++u)
      v[u] = *(const f16x8*)(row + (size_t)u * 4096);
    row += 4 * 4096;
#pragma unroll
    for (int u = 0; u < 4; ++u) {
      h0 = fmaf((float)v[u][0], h0, (float)v[u][1]);
      h1 = fmaf((float)v[u][2], h1, (float)v[u][3]);
      h2 = fmaf((float)v[u][4], h2, (float)v[u][5]);
      h3 = fmaf((float)v[u][6], h3, (float)v[u][7]);
      float4 o;
      o.x = h0;
      o.y = h1;
      o.z = h2;
      o.w = h3;
      *(float4*)(orow + (size_t)u * 2048) = o;
    }
    orow += 4 * 2048;
  }
}

extern "C" void kernel_launch(void* const* d_in, const int* in_sizes, int n_in,
                              void* d_out, int out_size, void* d_ws, size_t ws_size,
                              hipStream_t stream) {
  const float* x = (const float*)d_in[0];
  const float* Wa = (const float*)d_in[1];
  const float* ba = (const float*)d_in[2];
  const float* Wi = (const float*)d_in[3];
  const float* bi = (const float*)d_in[4];
  const float* gate = (const float*)d_in[5];
  float* out = (float*)d_out;

  char* ws = (char*)d_ws;
  _Float16* xh = (_Float16*)ws;               // 16 MiB
  _Float16* wh = (_Float16*)(ws + 16777216);  // 4 MiB (interleaved Wa/Wi)
  const size_t MN2 = (size_t)16384 * 4096;
  _Float16* AC = (_Float16*)(ws + 20971520);  // 128 MiB fp16 (a,c) interleaved
  float2* agg = (float2*)(ws + 20971520 + MN2 * 2);            // 8 MiB
  float* carry = (float*)(ws + 20971520 + MN2 * 2 + 8388608);  // 4 MiB

  cvt_all<<<10240, 256, 0, stream>>>(x, Wa, Wi, xh, wh);
  gemm_gate<<<dim3(32, 128), 256, 0, stream>>>(xh, wh, ba, bi, gate, AC, agg);
  scan_pass2<<<dim3(32, 8), 64, 0, stream>>>(agg, carry);
  scan_out<<<dim3(2, 64, 8), 256, 0, stream>>>(AC, carry, out);
}

// Round 3
// 338.964 us; speedup vs baseline: 1.0558x; 1.0150x over previous
//
#include <hip/hip_runtime.h>

// GatedRecurrentCell: pa/pi = x@W^T + b (fp16 MFMA) with gates FUSED into the
// GEMM epilogue; (a,c) stored fp16; chunked linear scan (64 chunks x 32 steps).
// Shapes: B=8 S=2048 D=512 I=2048. M=B*S=16384, N2=2*I=4096, K=D=512.
// W layout: interleaved rows (2i=Wa_i, 2i+1=Wi_i) so each n-tile holds (pa,pi)
// pairs for 64 i's -> epilogue computes a,c + 32-step chunk aggregates in-block.
// R3 == R2 pipeline with the launcher OOB fixed (scan_out grid dim3(2,64,8),
// NOT dim3(4,64,8) — tt*4 must stay < I=2048).
// R2: counted-vmcnt pipeline (T3/T4 minimum): 3-deep LDS ring (3x16KB), ONE raw
// s_barrier per K-step, s_waitcnt vmcnt(4) in steady state (never 0 until the
// last tile), sched_barrier(0) pins around the barrier.
// XOR slot swizzle (R1, verified: bank conflicts 8.4M -> 0) kept unchanged.
// ws: [0,16Mi) x_f16 | [16,20Mi) W_f16 | [20Mi,+128Mi) AC f16 | +8Mi agg | +4Mi carry

#define LOG2_3 1.5849625007211562f

typedef _Float16 f16x8 __attribute__((ext_vector_type(8)));
typedef _Float16 f16x4 __attribute__((ext_vector_type(4)));
typedef _Float16 f16x2 __attribute__((ext_vector_type(2)));
typedef float f32x4 __attribute__((ext_vector_type(4)));

__device__ __forceinline__ float sigmoidf_(float v) {
  return 1.0f / (1.0f + __expf(-v));
}

__device__ __forceinline__ void async_copy16(void* lds, const void* gp) {
  __builtin_amdgcn_global_load_lds((__attribute__((address_space(1))) void*)gp,
                                   (__attribute__((address_space(3))) void*)lds,
                                   16, 0, 0);
}

// x -> xh (plain). Wa/Wi -> wh with row interleave: wh row 2i = Wa_i, 2i+1 = Wi_i.
__global__ __launch_bounds__(256) void cvt_all(const float* __restrict__ x,
                                               const float* __restrict__ Wa,
                                               const float* __restrict__ Wi,
                                               _Float16* __restrict__ xh,
                                               _Float16* __restrict__ wh) {
  int idx = blockIdx.x * 256 + threadIdx.x;
  const float* src;
  _Float16* dst;
  int off, doff;
  if (idx < 2097152) {
    src = x; dst = xh; off = idx; doff = idx;
  } else if (idx < 2097152 + 262144) {
    src = Wa; dst = wh; off = idx - 2097152;
    doff = off + ((off >> 7) << 7);          // (2i)*128 + k4
  } else {
    src = Wi; dst = wh; off = idx - 2359296;
    doff = off + ((off >> 7) << 7) + 128;    // (2i+1)*128 + k4
  }
  float4 v = ((const float4*)src)[off];
  f16x4 h;
  h[0] = (_Float16)v.x;
  h[1] = (_Float16)v.y;
  h[2] = (_Float16)v.z;
  h[3] = (_Float16)v.w;
  ((f16x4*)dst)[doff] = h;
}

__device__ __forceinline__ void gate_ac(float pa, float pi, float alpha, float& a, float& c) {
  float rg = sigmoidf_(pa);
  a = alpha * exp2f(-LOG2_3 * rg);
  float ig = sigmoidf_(pi);
  c = sqrtf(fmaxf(1.0f - a * a, 0.0f)) * (ig * pi);
}

// GEMM 128x128 tile + fused gate epilogue.
// AC[m][2i..2i+1] = (a,c) fp16. agg[(b*64+ch)][i] = (A,H) over 32-step chunk.
// LDS: 3-deep ring of K-buffers, buf k = smem + 8192*k, each {As 4096 | Bs 4096}.
// Epilogue reuses smem[0,8704).
// Swizzle: 16B slot s at row r holds logical slot s ^ ((r>>1)&3). Staging keeps
// the LDS dest linear (t*16B, required by global_load_lds) and pre-swizzles the
// GLOBAL source column; reads apply the same XOR (involution).
__global__ __launch_bounds__(256) void gemm_gate(const _Float16* __restrict__ Ah,
                                                 const _Float16* __restrict__ Wh,
                                                 const float* __restrict__ ba,
                                                 const float* __restrict__ bi,
                                                 const float* __restrict__ gate,
                                                 _Float16* __restrict__ AC,
                                                 float2* __restrict__ agg) {
  constexpr int K = 512;
  constexpr int N2 = 4096;
  __shared__ __align__(16) _Float16 smem[24576];  // 48 KiB: 3 x (As 4096 | Bs 4096)
  __shared__ float pAs[8 * 65];                   // partials, padded stride 65
  __shared__ float pHs[8 * 65];
  const int t = threadIdx.x;
  const int mBase = blockIdx.y * 128;
  const int nBase = blockIdx.x * 128;
  const int r = t >> 2;                      // staged row (0..63; +64 for 2nd half)
  const int p = t & 3;                       // physical 16B slot within row
  const int lsw = p ^ ((r >> 1) & 3);        // logical slot to fetch for this dest
  const _Float16* gA0 = Ah + (size_t)(mBase + r) * K + lsw * 8;
  const _Float16* gB0 = Wh + (size_t)(nBase + r) * K + lsw * 8;
  const int ldst = r * 32 + p * 8;           // f16 idx; byte off == t*16 (linear)

  const int lane = t & 63;
  const int wave = t >> 6;
  const int wm = (wave & 1) * 64;
  const int wn = (wave >> 1) * 64;
  const int lrow = lane & 15;
  const int quad = lane >> 4;
  // read-side swizzled slot: row = (16-mult) + lrow -> f(row) = (lrow>>1)&3
  const int xq = quad ^ ((lrow >> 1) & 3);

  f32x4 acc[4][4];
#pragma unroll
  for (int i = 0; i < 4; ++i)
#pragma unroll
    for (int j = 0; j < 4; ++j)
      acc[i][j] = (f32x4)0.0f;

  // stage K-tile tt into ring buffer tt%3 (4 x global_load_lds, 16B each)
  auto STAGE = [&](int tt) {
    _Float16* bb = smem + 8192 * (tt % 3);
    const int ko = tt * 32;
    async_copy16(bb + ldst, gA0 + ko);
    async_copy16(bb + 2048 + ldst, gA0 + (size_t)64 * K + ko);
    async_copy16(bb + 4096 + ldst, gB0 + ko);
    async_copy16(bb + 6144 + ldst, gB0 + (size_t)64 * K + ko);
  };

  // prologue: tiles 0 and 1 in flight
  STAGE(0);
  STAGE(1);

  // Main loop: ONE barrier per K-step, counted vmcnt.
  //   wait vmcnt(4): tile kt's 4 loads landed; tile kt+1's may stay in flight.
  //   lgkmcnt(0): my ds_reads of buf[(kt-1)%3] complete -> after the barrier it
  //   is safe for ANY wave to overwrite that buffer (== buf[(kt+2)%3]).
  //   sched_barrier(0) pins: no memory op crosses the barrier (rule #18/#21).
#pragma unroll
  for (int kt = 0; kt < 16; ++kt) {
    if (kt == 15)
      asm volatile("s_waitcnt vmcnt(0) lgkmcnt(0)" ::: "memory");
    else
      asm volatile("s_waitcnt vmcnt(4) lgkmcnt(0)" ::: "memory");
    __builtin_amdgcn_sched_barrier(0);
    __builtin_amdgcn_s_barrier();
    __builtin_amdgcn_sched_barrier(0);
    if (kt < 14) STAGE(kt + 2);
    const _Float16* cur = smem + 8192 * (kt % 3);
    f16x8 af[4], bf[4];
#pragma unroll
    for (int i = 0; i < 4; ++i)
      af[i] = *(const f16x8*)(cur + (wm + i * 16 + lrow) * 32 + xq * 8);
#pragma unroll
    for (int j = 0; j < 4; ++j)
      bf[j] = *(const f16x8*)(cur + 4096 + (wn + j * 16 + lrow) * 32 + xq * 8);
#pragma unroll
    for (int i = 0; i < 4; ++i)
#pragma unroll
      for (int j = 0; j < 4; ++j)
        acc[i][j] = __builtin_amdgcn_mfma_f32_16x16x32_f16(af[i], bf[j], acc[i][j], 0, 0, 0);
  }
  // drain everything before the epilogue reuses smem[0,8704)
  __syncthreads();

  // bias: col n even -> ba[n/2] (pa), odd -> bi[n/2] (pi)
  float bias[4];
#pragma unroll
  for (int j = 0; j < 4; ++j) {
    const int n = nBase + wn + j * 16 + lrow;
    bias[j] = (n & 1) ? bi[n >> 1] : ba[n >> 1];
  }

  // gate-phase thread roles: col = i-lane 0..63, q = s-quarter (16 rows each)
  const int col = t & 63;
  const int q = t >> 6;
  const float alpha = sigmoidf_(gate[(nBase >> 1) + col]);
  const int b = blockIdx.y >> 4;  // 16 m-tiles per batch

  // 2 rounds of 64 m-rows: stage C+bias -> LDS, compute a,c, store AC, local scan.
  // C/D layout: col = lane&15, row = quad*4 + reg (m89-verified)
#pragma unroll
  for (int h = 0; h < 2; ++h) {
    if (wm == h * 64) {
#pragma unroll
      for (int i = 0; i < 4; ++i)
#pragma unroll
        for (int j = 0; j < 4; ++j)
#pragma unroll
          for (int rr = 0; rr < 4; ++rr)
            smem[(i * 16 + quad * 4 + rr) * 136 + wn + j * 16 + lrow] =
                (_Float16)(acc[i][j][rr] + bias[j]);
    }
    __syncthreads();
    float A = 1.0f, Hn = 0.0f;
    _Float16* ACp = AC + (size_t)(mBase + h * 64 + q * 16) * N2 + nBase + 2 * col;
#pragma unroll 4
    for (int rs = 0; rs < 16; ++rs) {
      f16x2 pp = *(const f16x2*)(smem + (q * 16 + rs) * 136 + 2 * col);
      float a, c;
      gate_ac((float)pp[0], (float)pp[1], alpha, a, c);
      f16x2 o;
      o[0] = (_Float16)a;
      o[1] = (_Float16)c;
      *(f16x2*)ACp = o;
      ACp += N2;
      A *= a;
      Hn = fmaf(a, Hn, c);
    }
    pAs[(h * 4 + q) * 65 + col] = A;
    pHs[(h * 4 + q) * 65 + col] = Hn;
    __syncthreads();
  }

  // combine 8x16-step partials -> 4x32-step aggregates (s-ascending pairs)
  if (t < 64) {
#pragma unroll
    for (int k = 0; k < 4; ++k) {
      float A0 = pAs[(2 * k) * 65 + t], H0 = pHs[(2 * k) * 65 + t];
      float A1 = pAs[(2 * k + 1) * 65 + t], H1 = pHs[(2 * k + 1) * 65 + t];
      const int ch = ((blockIdx.y & 15) << 2) + k;
      agg[((size_t)(b * 64 + ch)) * 2048 + (nBase >> 1) + t] =
          make_float2(A0 * A1, fmaf(A1, H0, H1));
    }
  }
}

__global__ __launch_bounds__(64) void scan_pass2(const float2* __restrict__ agg,
                                                 float* __restrict__ carry) {
  const int i = blockIdx.x * 64 + threadIdx.x;  // grid.x=32 -> 0..2047
  const int b = blockIdx.y;
  float h = 0.0f;
  for (int c8 = 0; c8 < 8; ++c8) {
    float2 aH[8];
#pragma unroll
    for (int u = 0; u < 8; ++u)
      aH[u] = agg[((size_t)(b * 64 + c8 * 8 + u)) * 2048 + i];
#pragma unroll
    for (int u = 0; u < 8; ++u) {
      carry[((size_t)(b * 64 + c8 * 8 + u)) * 2048 + i] = h;
      h = fmaf(aH[u].x, h, aH[u].y);
    }
  }
}

// Pure fma replay: h = a*h + c, no transcendentals. 4 i's per thread,
// f16x8 (16B) loads + float4 (16B) stores. grid.x=2 -> tt 0..511, i0 0..2047.
__global__ __launch_bounds__(256) void scan_out(const _Float16* __restrict__ AC,
                                                const float* __restrict__ carry,
                                                float* __restrict__ out) {
  const int tt = blockIdx.x * 256 + threadIdx.x;  // 0..511 (4 i's per thread)
  const int i0 = tt * 4;
  const int ch = blockIdx.y;  // 0..63
  const int b = blockIdx.z;
  const float4 cr = ((const float4*)(carry + ((size_t)(b * 64 + ch)) * 2048))[tt];
  float h0 = cr.x, h1 = cr.y, h2 = cr.z, h3 = cr.w;
  const _Float16* row = AC + ((size_t)(b * 2048 + ch * 32)) * 4096 + i0 * 2;
  float* orow = out + ((size_t)(b * 2048 + ch * 32)) * 2048 + i0;
  for (int s4 = 0; s4 < 8; ++s4) {
    f16x8 v[4];
#pragma unroll
    for (int u = 0; u < 4; ++u)
      v[u] = *(const f16x8*)(row + (size_t)u * 4096);
    row += 4 * 4096;
#pragma unroll
    for (int u = 0; u < 4; ++u) {
      h0 = fmaf((float)v[u][0], h0, (float)v[u][1]);
      h1 = fmaf((float)v[u][2], h1, (float)v[u][3]);
      h2 = fmaf((float)v[u][4], h2, (float)v[u][5]);
      h3 = fmaf((float)v[u][6], h3, (float)v[u][7]);
      float4 o;
      o.x = h0;
      o.y = h1;
      o.z = h2;
      o.w = h3;
      *(float4*)(orow + (size_t)u * 2048) = o;
    }
    orow += 4 * 2048;
  }
}

extern "C" void kernel_launch(void* const* d_in, const int* in_sizes, int n_in,
                              void* d_out, int out_size, void* d_ws, size_t ws_size,
                              hipStream_t stream) {
  const float* x = (const float*)d_in[0];
  const float* Wa = (const float*)d_in[1];
  const float* ba = (const float*)d_in[2];
  const float* Wi = (const float*)d_in[3];
  const float* bi = (const float*)d_in[4];
  const float* gate = (const float*)d_in[5];
  float* out = (float*)d_out;

  char* ws = (char*)d_ws;
  _Float16* xh = (_Float16*)ws;               // 16 MiB
  _Float16* wh = (_Float16*)(ws + 16777216);  // 4 MiB (interleaved Wa/Wi)
  const size_t MN2 = (size_t)16384 * 4096;
  _Float16* AC = (_Float16*)(ws + 20971520);  // 128 MiB fp16 (a,c) interleaved
  float2* agg = (float2*)(ws + 20971520 + MN2 * 2);            // 8 MiB
  float* carry = (float*)(ws + 20971520 + MN2 * 2 + 8388608);  // 4 MiB

  cvt_all<<<10240, 256, 0, stream>>>(x, Wa, Wi, xh, wh);
  gemm_gate<<<dim3(32, 128), 256, 0, stream>>>(xh, wh, ba, bi, gate, AC, agg);
  scan_pass2<<<dim3(32, 8), 64, 0, stream>>>(agg, carry);
  scan_out<<<dim3(2, 64, 8), 256, 0, stream>>>(AC, carry, out);
}

// Round 6
// 333.417 us; speedup vs baseline: 1.0734x; 1.0166x over previous
//
#include <hip/hip_runtime.h>

// GatedRecurrentCell: pa/pi = x@W^T + b (fp16 MFMA) with gates FUSED into the
// GEMM epilogue; (a,c) stored fp16; chunked linear scan (64 chunks x 32 steps).
// Shapes: B=8 S=2048 D=512 I=2048. M=B*S=16384, N2=2*I=4096, K=D=512.
// R6 == R4 with compile fix: __builtin_nontemporal_store needs a clang
// ext_vector pointer (f32x4), not HIP's float4 class type.
// R4: (a) K-loop = catalog "minimum 2-phase": 2-buffer LDS (32 KB -> 4 blocks/CU),
// STAGE(next-buf) issued BEFORE compute(cur), ONE __syncthreads per K-step.
// (b) epilogue fast math: __fdividef (v_rcp) sigmoids + m*__frsqrt_rn(m) sqrt.
// (c) scan_out: 2-deep prefetch ping-pong + nontemporal loads/stores.
// XOR slot swizzle kept (bank conflicts verified 0).
// ws: [0,16Mi) x_f16 | [16,20Mi) W_f16 | [20Mi,+128Mi) AC f16 | +8Mi agg | +4Mi carry

#define LOG2_3 1.5849625007211562f

typedef _Float16 f16x8 __attribute__((ext_vector_type(8)));
typedef _Float16 f16x4 __attribute__((ext_vector_type(4)));
typedef _Float16 f16x2 __attribute__((ext_vector_type(2)));
typedef float f32x4 __attribute__((ext_vector_type(4)));

__device__ __forceinline__ float sigmoid_fast(float v) {
  // v_exp + v_rcp path (no precise-divide sequence). |v| <= ~10 here.
  return __fdividef(1.0f, 1.0f + __expf(-v));
}

__device__ __forceinline__ void async_copy16(void* lds, const void* gp) {
  __builtin_amdgcn_global_load_lds((__attribute__((address_space(1))) void*)gp,
                                   (__attribute__((address_space(3))) void*)lds,
                                   16, 0, 0);
}

// x -> xh (plain). Wa/Wi -> wh with row interleave: wh row 2i = Wa_i, 2i+1 = Wi_i.
__global__ __launch_bounds__(256) void cvt_all(const float* __restrict__ x,
                                               const float* __restrict__ Wa,
                                               const float* __restrict__ Wi,
                                               _Float16* __restrict__ xh,
                                               _Float16* __restrict__ wh) {
  int idx = blockIdx.x * 256 + threadIdx.x;
  const float* src;
  _Float16* dst;
  int off, doff;
  if (idx < 2097152) {
    src = x; dst = xh; off = idx; doff = idx;
  } else if (idx < 2097152 + 262144) {
    src = Wa; dst = wh; off = idx - 2097152;
    doff = off + ((off >> 7) << 7);          // (2i)*128 + k4
  } else {
    src = Wi; dst = wh; off = idx - 2359296;
    doff = off + ((off >> 7) << 7) + 128;    // (2i+1)*128 + k4
  }
  float4 v = ((const float4*)src)[off];
  f16x4 h;
  h[0] = (_Float16)v.x;
  h[1] = (_Float16)v.y;
  h[2] = (_Float16)v.z;
  h[3] = (_Float16)v.w;
  ((f16x4*)dst)[doff] = h;
}

__device__ __forceinline__ void gate_ac(float pa, float pi, float alpha, float& a, float& c) {
  float rg = sigmoid_fast(pa);
  a = alpha * exp2f(-LOG2_3 * rg);
  float ig = sigmoid_fast(pi);
  // a <= 0.999 -> 1-a^2 >= ~2e-3; clamp well below that to avoid 0*inf.
  float m = fmaxf(1.0f - a * a, 1e-8f);
  c = (m * __frsqrt_rn(m)) * (ig * pi);  // sqrt(m) = m * rsqrt(m)
}

// GEMM 128x128 tile + fused gate epilogue.
// AC[m][2i..2i+1] = (a,c) fp16. agg[(b*64+ch)][i] = (A,H) over 32-step chunk.
// LDS: 2 K-buffers {As 4096 | Bs 4096} f16; epilogue reuses smem[0,8704).
// K-loop (minimum 2-phase): STAGE(nxt) -> ds_read(cur)+MFMA -> __syncthreads.
// The single barrier (vmcnt0+lgkm0 drain) makes iter kt's stage of buffer
// (kt+1)&1 safe: that buffer's readers finished before barrier kt-1.
// Swizzle: 16B slot s at row r holds logical slot s ^ ((r>>1)&3). Staging keeps
// the LDS dest linear (t*16B, required by global_load_lds) and pre-swizzles the
// GLOBAL source column; reads apply the same XOR (involution).
__global__ __launch_bounds__(256) void gemm_gate(const _Float16* __restrict__ Ah,
                                                 const _Float16* __restrict__ Wh,
                                                 const float* __restrict__ ba,
                                                 const float* __restrict__ bi,
                                                 const float* __restrict__ gate,
                                                 _Float16* __restrict__ AC,
                                                 float2* __restrict__ agg) {
  constexpr int K = 512;
  constexpr int N2 = 4096;
  __shared__ __align__(16) _Float16 smem[16384];  // 32 KiB: 2 x (As 4096 | Bs 4096)
  __shared__ float pAs[8 * 65];                   // partials, padded stride 65
  __shared__ float pHs[8 * 65];
  const int t = threadIdx.x;
  const int mBase = blockIdx.y * 128;
  const int nBase = blockIdx.x * 128;
  const int r = t >> 2;                      // staged row (0..63; +64 for 2nd half)
  const int p = t & 3;                       // physical 16B slot within row
  const int lsw = p ^ ((r >> 1) & 3);        // logical slot to fetch for this dest
  const _Float16* gA0 = Ah + (size_t)(mBase + r) * K + lsw * 8;
  const _Float16* gB0 = Wh + (size_t)(nBase + r) * K + lsw * 8;
  const int ldst = r * 32 + p * 8;           // f16 idx; byte off == t*16 (linear)

  const int lane = t & 63;
  const int wave = t >> 6;
  const int wm = (wave & 1) * 64;
  const int wn = (wave >> 1) * 64;
  const int lrow = lane & 15;
  const int quad = lane >> 4;
  // read-side swizzled slot: row = (16-mult) + lrow -> f(row) = (lrow>>1)&3
  const int xq = quad ^ ((lrow >> 1) & 3);

  f32x4 acc[4][4];
#pragma unroll
  for (int i = 0; i < 4; ++i)
#pragma unroll
    for (int j = 0; j < 4; ++j)
      acc[i][j] = (f32x4)0.0f;

  _Float16* b0 = smem;
  _Float16* b1 = smem + 8192;

  auto STAGE = [&](int tt, _Float16* bb) {
    const int ko = tt * 32;
    async_copy16(bb + ldst, gA0 + ko);
    async_copy16(bb + 2048 + ldst, gA0 + (size_t)64 * K + ko);
    async_copy16(bb + 4096 + ldst, gB0 + ko);
    async_copy16(bb + 6144 + ldst, gB0 + (size_t)64 * K + ko);
  };

  STAGE(0, b0);
  __syncthreads();

#pragma unroll
  for (int kt = 0; kt < 16; ++kt) {
    _Float16* cur = (kt & 1) ? b1 : b0;
    _Float16* nxt = (kt & 1) ? b0 : b1;
    if (kt < 15) STAGE(kt + 1, nxt);  // issue BEFORE compute; lands by next barrier
    f16x8 af[4], bf[4];
#pragma unroll
    for (int i = 0; i < 4; ++i)
      af[i] = *(const f16x8*)(cur + (wm + i * 16 + lrow) * 32 + xq * 8);
#pragma unroll
    for (int j = 0; j < 4; ++j)
      bf[j] = *(const f16x8*)(cur + 4096 + (wn + j * 16 + lrow) * 32 + xq * 8);
#pragma unroll
    for (int i = 0; i < 4; ++i)
#pragma unroll
      for (int j = 0; j < 4; ++j)
        acc[i][j] = __builtin_amdgcn_mfma_f32_16x16x32_f16(af[i], bf[j], acc[i][j], 0, 0, 0);
    // single barrier/K-step: drains stage (vmcnt) + my reads (lgkm), publishes nxt
    __syncthreads();
  }

  // bias: col n even -> ba[n/2] (pa), odd -> bi[n/2] (pi)
  float bias[4];
#pragma unroll
  for (int j = 0; j < 4; ++j) {
    const int n = nBase + wn + j * 16 + lrow;
    bias[j] = (n & 1) ? bi[n >> 1] : ba[n >> 1];
  }

  // gate-phase thread roles: col = i-lane 0..63, q = s-quarter (16 rows each)
  const int col = t & 63;
  const int q = t >> 6;
  const float alpha = sigmoid_fast(gate[(nBase >> 1) + col]);
  const int b = blockIdx.y >> 4;  // 16 m-tiles per batch

  // 2 rounds of 64 m-rows: stage C+bias -> LDS, compute a,c, store AC, local scan.
  // C/D layout: col = lane&15, row = quad*4 + reg (m89-verified)
#pragma unroll
  for (int h = 0; h < 2; ++h) {
    if (wm == h * 64) {
#pragma unroll
      for (int i = 0; i < 4; ++i)
#pragma unroll
        for (int j = 0; j < 4; ++j)
#pragma unroll
          for (int rr = 0; rr < 4; ++rr)
            smem[(i * 16 + quad * 4 + rr) * 136 + wn + j * 16 + lrow] =
                (_Float16)(acc[i][j][rr] + bias[j]);
    }
    __syncthreads();
    float A = 1.0f, Hn = 0.0f;
    _Float16* ACp = AC + (size_t)(mBase + h * 64 + q * 16) * N2 + nBase + 2 * col;
#pragma unroll 4
    for (int rs = 0; rs < 16; ++rs) {
      f16x2 pp = *(const f16x2*)(smem + (q * 16 + rs) * 136 + 2 * col);
      float a, c;
      gate_ac((float)pp[0], (float)pp[1], alpha, a, c);
      f16x2 o;
      o[0] = (_Float16)a;
      o[1] = (_Float16)c;
      *(f16x2*)ACp = o;
      ACp += N2;
      A *= a;
      Hn = fmaf(a, Hn, c);
    }
    pAs[(h * 4 + q) * 65 + col] = A;
    pHs[(h * 4 + q) * 65 + col] = Hn;
    __syncthreads();
  }

  // combine 8x16-step partials -> 4x32-step aggregates (s-ascending pairs)
  if (t < 64) {
#pragma unroll
    for (int k = 0; k < 4; ++k) {
      float A0 = pAs[(2 * k) * 65 + t], H0 = pHs[(2 * k) * 65 + t];
      float A1 = pAs[(2 * k + 1) * 65 + t], H1 = pHs[(2 * k + 1) * 65 + t];
      const int ch = ((blockIdx.y & 15) << 2) + k;
      agg[((size_t)(b * 64 + ch)) * 2048 + (nBase >> 1) + t] =
          make_float2(A0 * A1, fmaf(A1, H0, H1));
    }
  }
}

__global__ __launch_bounds__(64) void scan_pass2(const float2* __restrict__ agg,
                                                 float* __restrict__ carry) {
  const int i = blockIdx.x * 64 + threadIdx.x;  // grid.x=32 -> 0..2047
  const int b = blockIdx.y;
  float h = 0.0f;
  for (int c8 = 0; c8 < 8; ++c8) {
    float2 aH[8];
#pragma unroll
    for (int u = 0; u < 8; ++u)
      aH[u] = agg[((size_t)(b * 64 + c8 * 8 + u)) * 2048 + i];
#pragma unroll
    for (int u = 0; u < 8; ++u) {
      carry[((size_t)(b * 64 + c8 * 8 + u)) * 2048 + i] = h;
      h = fmaf(aH[u].x, h, aH[u].y);
    }
  }
}

// Pure fma replay: h = a*h + c. 4 i's per thread, f16x8 loads + f32x4 stores,
// 2-deep ping-pong prefetch (static indexing), nontemporal (read/write-once).
__global__ __launch_bounds__(256) void scan_out(const _Float16* __restrict__ AC,
                                                const float* __restrict__ carry,
                                                float* __restrict__ out) {
  const int tt = blockIdx.x * 256 + threadIdx.x;  // 0..511 (4 i's per thread)
  const int i0 = tt * 4;
  const int ch = blockIdx.y;  // 0..63
  const int b = blockIdx.z;
  const float4 cr = ((const float4*)(carry + ((size_t)(b * 64 + ch)) * 2048))[tt];
  float h0 = cr.x, h1 = cr.y, h2 = cr.z, h3 = cr.w;
  const _Float16* row = AC + ((size_t)(b * 2048 + ch * 32)) * 4096 + i0 * 2;
  float* orow = out + ((size_t)(b * 2048 + ch * 32)) * 2048 + i0;

  f16x8 va[4], vb[4];
#pragma unroll
  for (int u = 0; u < 4; ++u)
    va[u] = __builtin_nontemporal_load((const f16x8*)(row + (size_t)u * 4096));

#pragma unroll
  for (int p = 0; p < 8; ++p) {
    // prefetch group p+1 into the other buffer (static selection)
    if (p < 7) {
      const _Float16* nrow = row + (size_t)(p + 1) * 4 * 4096;
      f16x8* dst = (p & 1) ? va : vb;
#pragma unroll
      for (int u = 0; u < 4; ++u)
        dst[u] = __builtin_nontemporal_load((const f16x8*)(nrow + (size_t)u * 4096));
    }
    const f16x8* v = (p & 1) ? vb : va;
    float* op = orow + (size_t)p * 4 * 2048;
#pragma unroll
    for (int u = 0; u < 4; ++u) {
      h0 = fmaf((float)v[u][0], h0, (float)v[u][1]);
      h1 = fmaf((float)v[u][2], h1, (float)v[u][3]);
      h2 = fmaf((float)v[u][4], h2, (float)v[u][5]);
      h3 = fmaf((float)v[u][6], h3, (float)v[u][7]);
      f32x4 o;
      o[0] = h0;
      o[1] = h1;
      o[2] = h2;
      o[3] = h3;
      __builtin_nontemporal_store(o, (f32x4*)(op + (size_t)u * 2048));
    }
  }
}

extern "C" void kernel_launch(void* const* d_in, const int* in_sizes, int n_in,
                              void* d_out, int out_size, void* d_ws, size_t ws_size,
                              hipStream_t stream) {
  const float* x = (const float*)d_in[0];
  const float* Wa = (const float*)d_in[1];
  const float* ba = (const float*)d_in[2];
  const float* Wi = (const float*)d_in[3];
  const float* bi = (const float*)d_in[4];
  const float* gate = (const float*)d_in[5];
  float* out = (float*)d_out;

  char* ws = (char*)d_ws;
  _Float16* xh = (_Float16*)ws;               // 16 MiB
  _Float16* wh = (_Float16*)(ws + 16777216);  // 4 MiB (interleaved Wa/Wi)
  const size_t MN2 = (size_t)16384 * 4096;
  _Float16* AC = (_Float16*)(ws + 20971520);  // 128 MiB fp16 (a,c) interleaved
  float2* agg = (float2*)(ws + 20971520 + MN2 * 2);            // 8 MiB
  float* carry = (float*)(ws + 20971520 + MN2 * 2 + 8388608);  // 4 MiB

  cvt_all<<<10240, 256, 0, stream>>>(x, Wa, Wi, xh, wh);
  gemm_gate<<<dim3(32, 128), 256, 0, stream>>>(xh, wh, ba, bi, gate, AC, agg);
  scan_pass2<<<dim3(32, 8), 64, 0, stream>>>(agg, carry);
  scan_out<<<dim3(2, 64, 8), 256, 0, stream>>>(AC, carry, out);
}